// Round 6
// baseline (305.612 us; speedup 1.0000x reference)
//
#include <hip/hip_runtime.h>
#include <stdint.h>

#define NROWS 4096
#define NHID 1024
#define CC0 1675
#define CC1 5025
#define HEADSZ 1677
#define PD0 256
#define PD1 64
#define TSZ0 3350
#define TSZ1 45232
#define HPN (HEADSZ + PD0 + PD1)   // 1997: head + proj0 + proj1 fused B
#define TPC1 6
#define L2E 1.4426950408889634f
#define LN2 0.6931471805599453f

typedef __attribute__((ext_vector_type(8))) __bf16 bf16x8;
typedef __attribute__((ext_vector_type(4))) float f32x4;

__device__ __forceinline__ unsigned short f2bf(float f) {
  union { float f; uint32_t u; } v; v.f = f;
  return (unsigned short)((v.u + 0x7FFFu + ((v.u >> 16) & 1u)) >> 16);
}
__device__ __forceinline__ float bfl(uint32_t u) {
  union { uint32_t u; float f; } v; v.u = u << 16; return v.f;
}
__device__ __forceinline__ float bfh(uint32_t u) {
  union { uint32_t u; float f; } v; v.u = u & 0xFFFF0000u; return v.f;
}
__device__ __forceinline__ float bf1(unsigned short u) {
  union { uint32_t u; float f; } v; v.u = ((uint32_t)u) << 16; return v.f;
}
#define EXP2(x) __builtin_amdgcn_exp2f(x)

// ---- single fused conversion kernel (sizes in float4 units, compile-time) --
// x:1048576 | head_w:429312(xL2E) | p0:65536 | p1:16384 | w0:214400(xL2E) |
// w1:723712(xL2E). Dest regions are contiguous in ws in this exact order.
#define CV1 1048576
#define CV2 1477888
#define CV3 1543424
#define CV4 1559808
#define CV5 1774208
#define CV6 2497920
__global__ void conv_all(const float* __restrict__ x, const float* __restrict__ hw,
                         const float* __restrict__ p0, const float* __restrict__ p1,
                         const float* __restrict__ w0, const float* __restrict__ w1,
                         unsigned short* __restrict__ dst) {
  int stride = gridDim.x * blockDim.x;
  for (int i = blockIdx.x * blockDim.x + threadIdx.x; i < CV6; i += stride) {
    const float* src; int off; float sc;
    if (i < CV1)      { src = x;  off = i;       sc = 1.f; }
    else if (i < CV2) { src = hw; off = i - CV1; sc = L2E; }
    else if (i < CV3) { src = p0; off = i - CV2; sc = 1.f; }
    else if (i < CV4) { src = p1; off = i - CV3; sc = 1.f; }
    else if (i < CV5) { src = w0; off = i - CV4; sc = L2E; }
    else              { src = w1; off = i - CV5; sc = L2E; }
    float4 v = reinterpret_cast<const float4*>(src)[off];
    ushort4 o;
    o.x = f2bf(v.x * sc); o.y = f2bf(v.y * sc);
    o.z = f2bf(v.z * sc); o.w = f2bf(v.w * sc);
    reinterpret_cast<ushort4*>(dst)[i] = o;
  }
}

#define GLOAD(g, l) __builtin_amdgcn_global_load_lds( \
    (const __attribute__((address_space(1))) uint32_t*)(const void*)(g), \
    (__attribute__((address_space(3))) uint32_t*)(void*)(l), 16, 0, 0)

// Involution swizzle on byte offsets within an 8KB [128][32]-bf16 tile:
// XOR bits 4-6 with bits 7-9. Bank-verified (round 2): conflicts 0.
#define SWZB(L) ((L) ^ ((((L) >> 7) & 7) << 4))

// ---------------- LDS-pipeline GEMM (head+proj, cluster 0) ----------------
// B weights pre-scaled by log2(e) for sum cols => epilogue is a single exp2.
__global__ __launch_bounds__(256, 4)
void gemm_fused(const unsigned short* __restrict__ A, int lda,
                const unsigned short* __restrict__ B, int ldb,
                int N, int K, int tpc,
                const float* __restrict__ bias,
                float* __restrict__ sum_out,
                unsigned short* __restrict__ Cout, int ldc,
                int coutStart) {
  __shared__ __align__(16) unsigned short As[2][128 * 32];
  __shared__ __align__(16) unsigned short Bs[2][128 * 32];
  const int tid = threadIdx.x;
  const int lane = tid & 63;
  const int wid = tid >> 6;
  const int wrow = (wid >> 1) * 64;
  const int wcol = (wid & 1) * 64;
  const int lr = lane & 15, lg = lane >> 4;

  const int cpx = gridDim.x >> 3;
  const int sid = ((int)blockIdx.x & 7) * cpx + ((int)blockIdx.x >> 3);
  const int rowBlk = sid & 31;
  const int colChunk = sid >> 5;
  const int brow = rowBlk * 128;
  const int nTiles = (N + 127) >> 7;
  const int tile0 = colChunk * tpc;
  const int tile1 = min(tile0 + tpc, nTiles);
  const int nsteps = (tile1 - tile0) * (K >> 5);
  const int rowBase = brow + wrow;

  float sacc[4][4];
#pragma unroll
  for (int m = 0; m < 4; ++m)
#pragma unroll
    for (int r = 0; r < 4; ++r) sacc[m][r] = 0.f;

  auto stage = [&](int b, int tt, int kk) {
#pragma unroll
    for (int c = 0; c < 2; ++c) {
      int g = wid * 128 + c * 64 + lane;
      int L = g * 16;
      int S = SWZB(L);
      int row = S >> 6, ko = (S >> 4) & 3;
      GLOAD(A + (size_t)(brow + row) * lda + kk + ko * 8, (char*)As[b] + L);
      int bsrc = tt * 128 + row; bsrc = bsrc < N ? bsrc : N - 1;
      GLOAD(B + (size_t)bsrc * ldb + kk + ko * 8, (char*)Bs[b] + L);
    }
  };

  f32x4 acc[4][4];
#pragma unroll
  for (int m = 0; m < 4; ++m)
#pragma unroll
    for (int n = 0; n < 4; ++n) acc[m][n] = (f32x4){0.f, 0.f, 0.f, 0.f};

  stage(0, tile0, 0);
  asm volatile("s_waitcnt vmcnt(0)" ::: "memory");
  __builtin_amdgcn_s_barrier();

  int tile = tile0, k0 = 0;
  for (int s = 0; s < nsteps; ++s) {
    const int cur = s & 1;
    int k0n = k0 + 32, tn = tile;
    if (k0n == K) { k0n = 0; tn = tile + 1; }
    if (s + 1 < nsteps) stage(cur ^ 1, tn, k0n);

    bf16x8 af[4], bfv[4];
#pragma unroll
    for (int m = 0; m < 4; ++m)
      af[m] = *(const bf16x8*)((const char*)As[cur] +
                               SWZB((wrow + m * 16 + lr) * 64 + lg * 16));
#pragma unroll
    for (int n = 0; n < 4; ++n)
      bfv[n] = *(const bf16x8*)((const char*)Bs[cur] +
                                SWZB((wcol + n * 16 + lr) * 64 + lg * 16));
#pragma unroll
    for (int m = 0; m < 4; ++m)
#pragma unroll
      for (int n = 0; n < 4; ++n)
        acc[m][n] = __builtin_amdgcn_mfma_f32_16x16x32_bf16(af[m], bfv[n], acc[m][n], 0, 0, 0);

    if (tn != tile) {
      const int cb = tile * 128 + wcol;
#pragma unroll
      for (int m = 0; m < 4; ++m)
#pragma unroll
        for (int n = 0; n < 4; ++n) {
#pragma unroll
          for (int r = 0; r < 4; ++r) {
            int col = cb + n * 16 + lr;
            if (col < N) {
              float v = acc[m][n][r];
              if (Cout && col >= coutStart) {
                int row = rowBase + m * 16 + lg * 4 + r;
                Cout[(size_t)row * ldc + (col - coutStart)] = f2bf(v);
              } else {
                if (bias) v = fmaf(bias[col], L2E, v);  // v already scaled
                sacc[m][r] += EXP2(v);
              }
            }
          }
          acc[m][n] = (f32x4){0.f, 0.f, 0.f, 0.f};
        }
    }

    asm volatile("s_waitcnt vmcnt(0)" ::: "memory");
    __builtin_amdgcn_s_barrier();
    tile = tn; k0 = k0n;
  }

#pragma unroll
  for (int m = 0; m < 4; ++m)
#pragma unroll
    for (int r = 0; r < 4; ++r) {
      float s = sacc[m][r];
      s += __shfl_xor(s, 1); s += __shfl_xor(s, 2);
      s += __shfl_xor(s, 4); s += __shfl_xor(s, 8);
      if (lr == 0) atomicAdd(&sum_out[rowBase + m * 16 + lg * 4 + r], s);
    }
}

// ---------------- register-direct streaming GEMM (cluster 1) ----------------
// A = hb+PD0 [4096 x 64] (lda=320), B = w1b (pre-scaled by log2e). K=64:
// A frags loaded once; B frags global->reg; no LDS, no barriers.
#define LOADB1(t, b) do {                                               \
    int cb_ = (t) * 128 + wcol;                                         \
    _Pragma("unroll")                                                   \
    for (int n_ = 0; n_ < 4; ++n_) {                                    \
      int col_ = cb_ + n_ * 16 + lr;                                    \
      col_ = col_ < TSZ1 ? col_ : TSZ1 - 1;                             \
      const unsigned short* p_ = B + (size_t)col_ * PD1 + lg * 8;       \
      b[n_][0] = *(const bf16x8*)p_;                                    \
      b[n_][1] = *(const bf16x8*)(p_ + 32);                             \
    } } while (0)

#define COMPUTE1(t, b) do {                                             \
    f32x4 acc_[4][4];                                                   \
    _Pragma("unroll")                                                   \
    for (int m_ = 0; m_ < 4; ++m_)                                      \
      _Pragma("unroll")                                                 \
      for (int n_ = 0; n_ < 4; ++n_) {                                  \
        f32x4 a_ = (f32x4){0.f, 0.f, 0.f, 0.f};                         \
        a_ = __builtin_amdgcn_mfma_f32_16x16x32_bf16(af[m_][0], b[n_][0], a_, 0, 0, 0); \
        a_ = __builtin_amdgcn_mfma_f32_16x16x32_bf16(af[m_][1], b[n_][1], a_, 0, 0, 0); \
        acc_[m_][n_] = a_;                                              \
      }                                                                 \
    int cb_ = (t) * 128 + wcol;                                         \
    if (cb_ + 63 < TSZ1) {                                              \
      _Pragma("unroll")                                                 \
      for (int m_ = 0; m_ < 4; ++m_)                                    \
        _Pragma("unroll")                                               \
        for (int r_ = 0; r_ < 4; ++r_) {                                \
          float s_ = EXP2(acc_[m_][0][r_]) + EXP2(acc_[m_][1][r_])      \
                   + EXP2(acc_[m_][2][r_]) + EXP2(acc_[m_][3][r_]);     \
          sacc[m_][r_] += s_;                                           \
        }                                                               \
    } else {                                                            \
      _Pragma("unroll")                                                 \
      for (int m_ = 0; m_ < 4; ++m_)                                    \
        _Pragma("unroll")                                               \
        for (int r_ = 0; r_ < 4; ++r_) {                                \
          float s_ = 0.f;                                               \
          _Pragma("unroll")                                             \
          for (int n_ = 0; n_ < 4; ++n_)                                \
            if (cb_ + n_ * 16 + lr < TSZ1) s_ += EXP2(acc_[m_][n_][r_]); \
          sacc[m_][r_] += s_;                                           \
        }                                                               \
    } } while (0)

__global__ __launch_bounds__(256, 4)
void gemm_c1_reg(const unsigned short* __restrict__ A,
                 const unsigned short* __restrict__ B,
                 float* __restrict__ sum_out) {
  const int lane = threadIdx.x & 63;
  const int wid = threadIdx.x >> 6;
  const int lr = lane & 15, lg = lane >> 4;

  const int cpx = gridDim.x >> 3;
  const int sid = ((int)blockIdx.x & 7) * cpx + ((int)blockIdx.x >> 3);
  const int rowBlk = sid & 31;
  const int colChunk = sid >> 5;
  const int rowBase = rowBlk * 128 + (wid >> 1) * 64;
  const int wcol = (wid & 1) * 64;
  const int tile0 = colChunk * TPC1;

  bf16x8 af[4][2];
#pragma unroll
  for (int m = 0; m < 4; ++m) {
    const unsigned short* p = A + (size_t)(rowBase + m * 16 + lr) * (PD0 + PD1) + lg * 8;
    af[m][0] = *(const bf16x8*)p;
    af[m][1] = *(const bf16x8*)(p + 32);
  }

  float sacc[4][4];
#pragma unroll
  for (int m = 0; m < 4; ++m)
#pragma unroll
    for (int r = 0; r < 4; ++r) sacc[m][r] = 0.f;

  bf16x8 b0[4][2], b1[4][2];
  LOADB1(tile0, b0);
#pragma unroll 1
  for (int t = tile0; t < tile0 + TPC1; t += 2) {
    LOADB1(t + 1, b1);
    COMPUTE1(t, b0);
    if (t + 2 < tile0 + TPC1) LOADB1(t + 2, b0);
    COMPUTE1(t + 1, b1);
  }

#pragma unroll
  for (int m = 0; m < 4; ++m)
#pragma unroll
    for (int r = 0; r < 4; ++r) {
      float s = sacc[m][r];
      s += __shfl_xor(s, 1); s += __shfl_xor(s, 2);
      s += __shfl_xor(s, 4); s += __shfl_xor(s, 8);
      if (lr == 0) atomicAdd(&sum_out[rowBase + m * 16 + lg * 4 + r], s);
    }
}

// One wave per row: target logits via direct dot products.
// hwb/w0b/w1b are log2e-scaled: head dot * LN2; cluster dot stays scaled
// (finalize multiplies tc by LN2).
__global__ void target_logits(const unsigned short* __restrict__ xb,
                              const unsigned short* __restrict__ hwb,
                              const float* __restrict__ head_b,
                              const unsigned short* __restrict__ hb,
                              const unsigned short* __restrict__ w0b,
                              const unsigned short* __restrict__ w1b,
                              const int* __restrict__ y,
                              float* __restrict__ ht, float* __restrict__ tc) {
  int row = blockIdx.x * 4 + (threadIdx.x >> 6);
  int lane = threadIdx.x & 63;
  int yv = y[row];
  int th = yv < CC0 ? yv : (yv < CC1 ? CC0 : CC0 + 1);

  const unsigned short* xr = xb + (size_t)row * NHID + lane * 16;
  const unsigned short* wr = hwb + (size_t)th * NHID + lane * 16;
  uint4 xa = *(const uint4*)xr,       wa = *(const uint4*)wr;
  uint4 xc = *(const uint4*)(xr + 8), wc = *(const uint4*)(wr + 8);
  float s = 0.f;
  uint32_t xs[8] = {xa.x, xa.y, xa.z, xa.w, xc.x, xc.y, xc.z, xc.w};
  uint32_t ws[8] = {wa.x, wa.y, wa.z, wa.w, wc.x, wc.y, wc.z, wc.w};
#pragma unroll
  for (int j = 0; j < 8; ++j)
    s += bfl(xs[j]) * bfl(ws[j]) + bfh(xs[j]) * bfh(ws[j]);
#pragma unroll
  for (int d = 1; d < 64; d <<= 1) s += __shfl_xor(s, d);

  float cl = 0.f;
  if (yv >= CC0) {
    if (yv < CC1) {
      int rel = yv - CC0;
      const unsigned short* hr = hb + (size_t)row * (PD0 + PD1) + lane * 4;
      const unsigned short* w0r = w0b + (size_t)rel * PD0 + lane * 4;
      uint2 ha = *(const uint2*)hr, wa0 = *(const uint2*)w0r;
      cl = bfl(ha.x) * bfl(wa0.x) + bfh(ha.x) * bfh(wa0.x)
         + bfl(ha.y) * bfl(wa0.y) + bfh(ha.y) * bfh(wa0.y);
    } else {
      int rel = yv - CC1;
      cl = bf1(hb[(size_t)row * (PD0 + PD1) + PD0 + lane])
         * bf1(w1b[(size_t)rel * PD1 + lane]);
    }
#pragma unroll
    for (int d = 1; d < 64; d <<= 1) cl += __shfl_xor(cl, d);
  }
  if (lane == 0) { ht[row] = s * LN2 + head_b[th]; tc[row] = (yv < CC0) ? 0.f : cl; }
}

__global__ void finalize_kernel(const float* __restrict__ hs, const float* __restrict__ ht,
                                const float* __restrict__ s0, const float* __restrict__ s1,
                                const float* __restrict__ tc,
                                const int* __restrict__ y, float* __restrict__ out) {
  __shared__ float red[256];
  float local = 0.f;
  for (int n = threadIdx.x; n < NROWS; n += 256) {
    int yv = y[n];
    float o = ht[n] - logf(hs[n]);
    if (yv >= CC0) o += tc[n] * LN2 - logf(yv < CC1 ? s0[n] : s1[n]);
    out[n] = o;
    local += o;
  }
  red[threadIdx.x] = local;
  __syncthreads();
  for (int s = 128; s > 0; s >>= 1) {
    if ((int)threadIdx.x < s) red[threadIdx.x] += red[threadIdx.x + s];
    __syncthreads();
  }
  if (threadIdx.x == 0) out[NROWS] = -red[0] / (float)NROWS;
}

extern "C" void kernel_launch(void* const* d_in, const int* in_sizes, int n_in,
                              void* d_out, int out_size, void* d_ws, size_t ws_size,
                              hipStream_t stream) {
  const float* x      = (const float*)d_in[0];
  const int*   y      = (const int*)d_in[1];
  const float* head_w = (const float*)d_in[2];
  const float* head_b = (const float*)d_in[3];
  const float* proj0  = (const float*)d_in[4];
  const float* w0     = (const float*)d_in[5];
  const float* proj1  = (const float*)d_in[6];
  const float* w1     = (const float*)d_in[7];
  float* out = (float*)d_out;

  char* wp = (char*)d_ws;
  unsigned short* xb  = (unsigned short*)wp; wp += (size_t)NROWS * NHID * 2;
  unsigned short* hpb = (unsigned short*)wp; wp += (size_t)HPN * NHID * 2;
  unsigned short* w0b = (unsigned short*)wp; wp += (size_t)TSZ0 * PD0 * 2;
  unsigned short* w1b = (unsigned short*)wp; wp += (size_t)TSZ1 * PD1 * 2;
  unsigned short* hb  = (unsigned short*)wp; wp += (size_t)NROWS * (PD0 + PD1) * 2;
  float* hs = (float*)wp; wp += NROWS * 4;
  float* s0 = (float*)wp; wp += NROWS * 4;
  float* s1 = (float*)wp; wp += NROWS * 4;
  float* ht = (float*)wp; wp += NROWS * 4;
  float* tc = (float*)wp; wp += NROWS * 4;

  hipMemsetAsync(hs, 0, 3 * NROWS * 4, stream);   // zero hs, s0, s1

  // single fused conversion (head_w/w0/w1 pre-scaled by log2e)
  conv_all<<<dim3(2048), 256, 0, stream>>>(x, head_w, proj0, proj1, w0, w1, xb);

  // head + proj fused: cols [0,1677) -> exp2-sum; cols [1677,1997) -> hb store
  gemm_fused<<<dim3(512), 256, 0, stream>>>(
      xb, NHID, hpb, NHID, HPN, NHID, 1,
      head_b, hs, hb, PD0 + PD1, HEADSZ);
  // target logits (needs hb) — one wave per row
  target_logits<<<dim3(NROWS / 4), 256, 0, stream>>>(
      xb, hpb, head_b, hb, w0b, w1b, y, ht, tc);
  // cluster 0: nTiles=27, tpc=1 -> 27 chunks x 32 = 864 blocks, 8-step chains
  gemm_fused<<<dim3(864), 256, 0, stream>>>(
      hb, PD0 + PD1, w0b, PD0, TSZ0, PD0, 1,
      nullptr, s0, nullptr, 0, 0);
  // cluster 1: register-direct, no LDS: 59 chunks x 32 rowBlks = 1888 blocks
  gemm_c1_reg<<<dim3(1888), 256, 0, stream>>>(hb + PD0, w1b, s1);

  finalize_kernel<<<1, 256, 0, stream>>>(hs, ht, s0, s1, tc, y, out);
}

// Round 7
// 156.611 us; speedup vs baseline: 1.9514x; 1.9514x over previous
//
#include <hip/hip_runtime.h>
#include <stdint.h>

#define NROWS 4096
#define NHID 1024
#define CC0 1675
#define CC1 5025
#define HEADSZ 1677
#define PD0 256
#define PD1 64
#define TSZ0 3350
#define TSZ1 45232
#define HPN (HEADSZ + PD0 + PD1)   // 1997: head + proj0 + proj1 fused B
#define TPC1 6
#define L2E 1.4426950408889634f
#define LN2 0.6931471805599453f

typedef __attribute__((ext_vector_type(8))) __bf16 bf16x8;
typedef __attribute__((ext_vector_type(4))) float f32x4;

__device__ __forceinline__ unsigned short f2bf(float f) {
  union { float f; uint32_t u; } v; v.f = f;
  return (unsigned short)((v.u + 0x7FFFu + ((v.u >> 16) & 1u)) >> 16);
}
__device__ __forceinline__ float bfl(uint32_t u) {
  union { uint32_t u; float f; } v; v.u = u << 16; return v.f;
}
__device__ __forceinline__ float bfh(uint32_t u) {
  union { uint32_t u; float f; } v; v.u = u & 0xFFFF0000u; return v.f;
}
__device__ __forceinline__ float bf1(unsigned short u) {
  union { uint32_t u; float f; } v; v.u = ((uint32_t)u) << 16; return v.f;
}
#define EXP2(x) __builtin_amdgcn_exp2f(x)

// ---- single fused conversion kernel (sizes in float4 units, compile-time) --
#define CV1 1048576
#define CV2 1477888
#define CV3 1543424
#define CV4 1559808
#define CV5 1774208
#define CV6 2497920
__global__ void conv_all(const float* __restrict__ x, const float* __restrict__ hw,
                         const float* __restrict__ p0, const float* __restrict__ p1,
                         const float* __restrict__ w0, const float* __restrict__ w1,
                         unsigned short* __restrict__ dst) {
  int stride = gridDim.x * blockDim.x;
  for (int i = blockIdx.x * blockDim.x + threadIdx.x; i < CV6; i += stride) {
    const float* src; int off; float sc;
    if (i < CV1)      { src = x;  off = i;       sc = 1.f; }
    else if (i < CV2) { src = hw; off = i - CV1; sc = L2E; }
    else if (i < CV3) { src = p0; off = i - CV2; sc = 1.f; }
    else if (i < CV4) { src = p1; off = i - CV3; sc = 1.f; }
    else if (i < CV5) { src = w0; off = i - CV4; sc = L2E; }
    else              { src = w1; off = i - CV5; sc = L2E; }
    float4 v = reinterpret_cast<const float4*>(src)[off];
    ushort4 o;
    o.x = f2bf(v.x * sc); o.y = f2bf(v.y * sc);
    o.z = f2bf(v.z * sc); o.w = f2bf(v.w * sc);
    reinterpret_cast<ushort4*>(dst)[i] = o;
  }
}

#define GLOAD(g, l) __builtin_amdgcn_global_load_lds( \
    (const __attribute__((address_space(1))) uint32_t*)(const void*)(g), \
    (__attribute__((address_space(3))) uint32_t*)(void*)(l), 16, 0, 0)

// Involution swizzle on byte offsets within an 8KB [128][32]-bf16 tile:
// XOR bits 4-6 with bits 7-9. Bank-verified (round 2): conflicts 0.
#define SWZB(L) ((L) ^ ((((L) >> 7) & 7) << 4))

// ---------------- LDS ring-pipeline GEMM (head+proj, cluster 0) ------------
// 3-buffer ring, counted vmcnt(4): stage s+2 in flight while computing s.
// Per iter: vmcnt(4) [stage s landed] -> s_barrier [all waves] ->
//           stage(s+2) -> ds_read + MFMA (+ epilogue at tile end).
// tpc==1 everywhere => epilogue (bias loads / Cout stores) only in the final
// iter, so it never perturbs the counted waits.
__global__ __launch_bounds__(256, 2)
void gemm_fused(const unsigned short* __restrict__ A, int lda,
                const unsigned short* __restrict__ B, int ldb,
                int N, int K, int tpc,
                const float* __restrict__ bias,
                float* __restrict__ sum_out,
                unsigned short* __restrict__ Cout, int ldc,
                int coutStart) {
  __shared__ __align__(16) unsigned short As[3][128 * 32];
  __shared__ __align__(16) unsigned short Bs[3][128 * 32];
  const int tid = threadIdx.x;
  const int lane = tid & 63;
  const int wid = tid >> 6;
  const int wrow = (wid >> 1) * 64;
  const int wcol = (wid & 1) * 64;
  const int lr = lane & 15, lg = lane >> 4;

  const int cpx = gridDim.x >> 3;
  const int sid = ((int)blockIdx.x & 7) * cpx + ((int)blockIdx.x >> 3);
  const int rowBlk = sid & 31;
  const int colChunk = sid >> 5;
  const int brow = rowBlk * 128;
  const int nTiles = (N + 127) >> 7;
  const int tile0 = colChunk * tpc;
  const int tile1 = min(tile0 + tpc, nTiles);
  const int nsteps = (tile1 - tile0) * (K >> 5);
  const int rowBase = brow + wrow;

  float sacc[4][4];
#pragma unroll
  for (int m = 0; m < 4; ++m)
#pragma unroll
    for (int r = 0; r < 4; ++r) sacc[m][r] = 0.f;

  auto stage = [&](int b, int tt, int kk) {
#pragma unroll
    for (int c = 0; c < 2; ++c) {
      int g = wid * 128 + c * 64 + lane;
      int L = g * 16;
      int S = SWZB(L);
      int row = S >> 6, ko = (S >> 4) & 3;
      GLOAD(A + (size_t)(brow + row) * lda + kk + ko * 8, (char*)As[b] + L);
      int bsrc = tt * 128 + row; bsrc = bsrc < N ? bsrc : N - 1;
      GLOAD(B + (size_t)bsrc * ldb + kk + ko * 8, (char*)Bs[b] + L);
    }
  };

  f32x4 acc[4][4];
#pragma unroll
  for (int m = 0; m < 4; ++m)
#pragma unroll
    for (int n = 0; n < 4; ++n) acc[m][n] = (f32x4){0.f, 0.f, 0.f, 0.f};

  // prefetch walker (points at the next step to stage)
  int tp = tile0, kp = 0;
  auto adv = [&](int& t, int& k) { k += 32; if (k == K) { k = 0; ++t; } };
  stage(0, tp, kp); adv(tp, kp);
  if (nsteps > 1) { stage(1, tp, kp); adv(tp, kp); }

  int tile = tile0, k0 = 0;
  for (int s = 0; s < nsteps; ++s) {
    if (s + 1 < nsteps) asm volatile("s_waitcnt vmcnt(4)" ::: "memory");
    else                asm volatile("s_waitcnt vmcnt(0)" ::: "memory");
    __builtin_amdgcn_s_barrier();          // all waves: stage(s) landed,
                                           // compute(s-1) finished
    if (s + 2 < nsteps) { stage((s + 2) % 3, tp, kp); adv(tp, kp); }

    const int cur = s % 3;
    int k0n = k0 + 32, tn = tile;
    if (k0n == K) { k0n = 0; tn = tile + 1; }

    bf16x8 af[4], bfv[4];
#pragma unroll
    for (int m = 0; m < 4; ++m)
      af[m] = *(const bf16x8*)((const char*)As[cur] +
                               SWZB((wrow + m * 16 + lr) * 64 + lg * 16));
#pragma unroll
    for (int n = 0; n < 4; ++n)
      bfv[n] = *(const bf16x8*)((const char*)Bs[cur] +
                                SWZB((wcol + n * 16 + lr) * 64 + lg * 16));
#pragma unroll
    for (int m = 0; m < 4; ++m)
#pragma unroll
      for (int n = 0; n < 4; ++n)
        acc[m][n] = __builtin_amdgcn_mfma_f32_16x16x32_bf16(af[m], bfv[n], acc[m][n], 0, 0, 0);

    if (tn != tile) {                      // tile finished: fused epilogue
      const int cb = tile * 128 + wcol;
#pragma unroll
      for (int m = 0; m < 4; ++m)
#pragma unroll
        for (int n = 0; n < 4; ++n) {
#pragma unroll
          for (int r = 0; r < 4; ++r) {
            int col = cb + n * 16 + lr;
            if (col < N) {
              float v = acc[m][n][r];
              if (Cout && col >= coutStart) {
                int row = rowBase + m * 16 + lg * 4 + r;
                Cout[(size_t)row * ldc + (col - coutStart)] = f2bf(v);
              } else {
                if (bias) v = fmaf(bias[col], L2E, v);  // v already log2e-scaled
                sacc[m][r] += EXP2(v);
              }
            }
          }
          acc[m][n] = (f32x4){0.f, 0.f, 0.f, 0.f};
        }
    }
    tile = tn; k0 = k0n;
  }

#pragma unroll
  for (int m = 0; m < 4; ++m)
#pragma unroll
    for (int r = 0; r < 4; ++r) {
      float s = sacc[m][r];
      s += __shfl_xor(s, 1); s += __shfl_xor(s, 2);
      s += __shfl_xor(s, 4); s += __shfl_xor(s, 8);
      if (lr == 0) atomicAdd(&sum_out[rowBase + m * 16 + lg * 4 + r], s);
    }
}

// ---------------- register-direct streaming GEMM (cluster 1) ----------------
// A = hb+PD0 [4096 x 64] (lda=320), B = w1b (pre-scaled by log2e). K=64:
// A frags loaded once; B frags global->reg; no LDS, no barriers.
// NOTE: register-budget-critical — launch_bounds MUST stay (256,2); (256,4)
// spills (round 6: VGPR 64, 583MB scratch writes, 3x regression).
#define LOADB1(t, b) do {                                               \
    int cb_ = (t) * 128 + wcol;                                         \
    _Pragma("unroll")                                                   \
    for (int n_ = 0; n_ < 4; ++n_) {                                    \
      int col_ = cb_ + n_ * 16 + lr;                                    \
      col_ = col_ < TSZ1 ? col_ : TSZ1 - 1;                             \
      const unsigned short* p_ = B + (size_t)col_ * PD1 + lg * 8;       \
      b[n_][0] = *(const bf16x8*)p_;                                    \
      b[n_][1] = *(const bf16x8*)(p_ + 32);                             \
    } } while (0)

#define COMPUTE1(t, b) do {                                             \
    f32x4 acc_[4][4];                                                   \
    _Pragma("unroll")                                                   \
    for (int m_ = 0; m_ < 4; ++m_)                                      \
      _Pragma("unroll")                                                 \
      for (int n_ = 0; n_ < 4; ++n_) {                                  \
        f32x4 a_ = (f32x4){0.f, 0.f, 0.f, 0.f};                         \
        a_ = __builtin_amdgcn_mfma_f32_16x16x32_bf16(af[m_][0], b[n_][0], a_, 0, 0, 0); \
        a_ = __builtin_amdgcn_mfma_f32_16x16x32_bf16(af[m_][1], b[n_][1], a_, 0, 0, 0); \
        acc_[m_][n_] = a_;                                              \
      }                                                                 \
    int cb_ = (t) * 128 + wcol;                                         \
    if (cb_ + 63 < TSZ1) {                                              \
      _Pragma("unroll")                                                 \
      for (int m_ = 0; m_ < 4; ++m_)                                    \
        _Pragma("unroll")                                               \
        for (int r_ = 0; r_ < 4; ++r_) {                                \
          float s_ = EXP2(acc_[m_][0][r_]) + EXP2(acc_[m_][1][r_])      \
                   + EXP2(acc_[m_][2][r_]) + EXP2(acc_[m_][3][r_]);     \
          sacc[m_][r_] += s_;                                           \
        }                                                               \
    } else {                                                            \
      _Pragma("unroll")                                                 \
      for (int m_ = 0; m_ < 4; ++m_)                                    \
        _Pragma("unroll")                                               \
        for (int r_ = 0; r_ < 4; ++r_) {                                \
          float s_ = 0.f;                                               \
          _Pragma("unroll")                                             \
          for (int n_ = 0; n_ < 4; ++n_)                                \
            if (cb_ + n_ * 16 + lr < TSZ1) s_ += EXP2(acc_[m_][n_][r_]); \
          sacc[m_][r_] += s_;                                           \
        }                                                               \
    } } while (0)

__global__ __launch_bounds__(256, 2)
void gemm_c1_reg(const unsigned short* __restrict__ A,
                 const unsigned short* __restrict__ B,
                 float* __restrict__ sum_out) {
  const int lane = threadIdx.x & 63;
  const int wid = threadIdx.x >> 6;
  const int lr = lane & 15, lg = lane >> 4;

  const int cpx = gridDim.x >> 3;
  const int sid = ((int)blockIdx.x & 7) * cpx + ((int)blockIdx.x >> 3);
  const int rowBlk = sid & 31;
  const int colChunk = sid >> 5;
  const int rowBase = rowBlk * 128 + (wid >> 1) * 64;
  const int wcol = (wid & 1) * 64;
  const int tile0 = colChunk * TPC1;

  bf16x8 af[4][2];
#pragma unroll
  for (int m = 0; m < 4; ++m) {
    const unsigned short* p = A + (size_t)(rowBase + m * 16 + lr) * (PD0 + PD1) + lg * 8;
    af[m][0] = *(const bf16x8*)p;
    af[m][1] = *(const bf16x8*)(p + 32);
  }

  float sacc[4][4];
#pragma unroll
  for (int m = 0; m < 4; ++m)
#pragma unroll
    for (int r = 0; r < 4; ++r) sacc[m][r] = 0.f;

  bf16x8 b0[4][2], b1[4][2];
  LOADB1(tile0, b0);
#pragma unroll 1
  for (int t = tile0; t < tile0 + TPC1; t += 2) {
    LOADB1(t + 1, b1);
    COMPUTE1(t, b0);
    if (t + 2 < tile0 + TPC1) LOADB1(t + 2, b0);
    COMPUTE1(t + 1, b1);
  }

#pragma unroll
  for (int m = 0; m < 4; ++m)
#pragma unroll
    for (int r = 0; r < 4; ++r) {
      float s = sacc[m][r];
      s += __shfl_xor(s, 1); s += __shfl_xor(s, 2);
      s += __shfl_xor(s, 4); s += __shfl_xor(s, 8);
      if (lr == 0) atomicAdd(&sum_out[rowBase + m * 16 + lg * 4 + r], s);
    }
}

// One wave per row: target logits via direct dot products.
// hwb/w0b/w1b are log2e-scaled: head dot * LN2; cluster dot stays scaled
// (finalize multiplies tc by LN2).
__global__ void target_logits(const unsigned short* __restrict__ xb,
                              const unsigned short* __restrict__ hwb,
                              const float* __restrict__ head_b,
                              const unsigned short* __restrict__ hb,
                              const unsigned short* __restrict__ w0b,
                              const unsigned short* __restrict__ w1b,
                              const int* __restrict__ y,
                              float* __restrict__ ht, float* __restrict__ tc) {
  int row = blockIdx.x * 4 + (threadIdx.x >> 6);
  int lane = threadIdx.x & 63;
  int yv = y[row];
  int th = yv < CC0 ? yv : (yv < CC1 ? CC0 : CC0 + 1);

  const unsigned short* xr = xb + (size_t)row * NHID + lane * 16;
  const unsigned short* wr = hwb + (size_t)th * NHID + lane * 16;
  uint4 xa = *(const uint4*)xr,       wa = *(const uint4*)wr;
  uint4 xc = *(const uint4*)(xr + 8), wc = *(const uint4*)(wr + 8);
  float s = 0.f;
  uint32_t xs[8] = {xa.x, xa.y, xa.z, xa.w, xc.x, xc.y, xc.z, xc.w};
  uint32_t ws[8] = {wa.x, wa.y, wa.z, wa.w, wc.x, wc.y, wc.z, wc.w};
#pragma unroll
  for (int j = 0; j < 8; ++j)
    s += bfl(xs[j]) * bfl(ws[j]) + bfh(xs[j]) * bfh(ws[j]);
#pragma unroll
  for (int d = 1; d < 64; d <<= 1) s += __shfl_xor(s, d);

  float cl = 0.f;
  if (yv >= CC0) {
    if (yv < CC1) {
      int rel = yv - CC0;
      const unsigned short* hr = hb + (size_t)row * (PD0 + PD1) + lane * 4;
      const unsigned short* w0r = w0b + (size_t)rel * PD0 + lane * 4;
      uint2 ha = *(const uint2*)hr, wa0 = *(const uint2*)w0r;
      cl = bfl(ha.x) * bfl(wa0.x) + bfh(ha.x) * bfh(wa0.x)
         + bfl(ha.y) * bfl(wa0.y) + bfh(ha.y) * bfh(wa0.y);
    } else {
      int rel = yv - CC1;
      cl = bf1(hb[(size_t)row * (PD0 + PD1) + PD0 + lane])
         * bf1(w1b[(size_t)rel * PD1 + lane]);
    }
#pragma unroll
    for (int d = 1; d < 64; d <<= 1) cl += __shfl_xor(cl, d);
  }
  if (lane == 0) { ht[row] = s * LN2 + head_b[th]; tc[row] = (yv < CC0) ? 0.f : cl; }
}

__global__ void finalize_kernel(const float* __restrict__ hs, const float* __restrict__ ht,
                                const float* __restrict__ s0, const float* __restrict__ s1,
                                const float* __restrict__ tc,
                                const int* __restrict__ y, float* __restrict__ out) {
  __shared__ float red[256];
  float local = 0.f;
  for (int n = threadIdx.x; n < NROWS; n += 256) {
    int yv = y[n];
    float o = ht[n] - logf(hs[n]);
    if (yv >= CC0) o += tc[n] * LN2 - logf(yv < CC1 ? s0[n] : s1[n]);
    out[n] = o;
    local += o;
  }
  red[threadIdx.x] = local;
  __syncthreads();
  for (int s = 128; s > 0; s >>= 1) {
    if ((int)threadIdx.x < s) red[threadIdx.x] += red[threadIdx.x + s];
    __syncthreads();
  }
  if (threadIdx.x == 0) out[NROWS] = -red[0] / (float)NROWS;
}

extern "C" void kernel_launch(void* const* d_in, const int* in_sizes, int n_in,
                              void* d_out, int out_size, void* d_ws, size_t ws_size,
                              hipStream_t stream) {
  const float* x      = (const float*)d_in[0];
  const int*   y      = (const int*)d_in[1];
  const float* head_w = (const float*)d_in[2];
  const float* head_b = (const float*)d_in[3];
  const float* proj0  = (const float*)d_in[4];
  const float* w0     = (const float*)d_in[5];
  const float* proj1  = (const float*)d_in[6];
  const float* w1     = (const float*)d_in[7];
  float* out = (float*)d_out;

  char* wp = (char*)d_ws;
  unsigned short* xb  = (unsigned short*)wp; wp += (size_t)NROWS * NHID * 2;
  unsigned short* hpb = (unsigned short*)wp; wp += (size_t)HPN * NHID * 2;
  unsigned short* w0b = (unsigned short*)wp; wp += (size_t)TSZ0 * PD0 * 2;
  unsigned short* w1b = (unsigned short*)wp; wp += (size_t)TSZ1 * PD1 * 2;
  unsigned short* hb  = (unsigned short*)wp; wp += (size_t)NROWS * (PD0 + PD1) * 2;
  float* hs = (float*)wp; wp += NROWS * 4;
  float* s0 = (float*)wp; wp += NROWS * 4;
  float* s1 = (float*)wp; wp += NROWS * 4;
  float* ht = (float*)wp; wp += NROWS * 4;
  float* tc = (float*)wp; wp += NROWS * 4;

  hipMemsetAsync(hs, 0, 3 * NROWS * 4, stream);   // zero hs, s0, s1

  // single fused conversion (head_w/w0/w1 pre-scaled by log2e)
  conv_all<<<dim3(2048), 256, 0, stream>>>(x, head_w, proj0, proj1, w0, w1, xb);

  // head + proj fused: cols [0,1677) -> exp2-sum; cols [1677,1997) -> hb store
  gemm_fused<<<dim3(512), 256, 0, stream>>>(
      xb, NHID, hpb, NHID, HPN, NHID, 1,
      head_b, hs, hb, PD0 + PD1, HEADSZ);
  // target logits (needs hb) — one wave per row
  target_logits<<<dim3(NROWS / 4), 256, 0, stream>>>(
      xb, hpb, head_b, hb, w0b, w1b, y, ht, tc);
  // cluster 0: nTiles=27, tpc=1 -> 27 chunks x 32 = 864 blocks, 8-step chains
  gemm_fused<<<dim3(864), 256, 0, stream>>>(
      hb, PD0 + PD1, w0b, PD0, TSZ0, PD0, 1,
      nullptr, s0, nullptr, 0, 0);
  // cluster 1: register-direct, no LDS: 59 chunks x 32 rowBlks = 1888 blocks
  gemm_c1_reg<<<dim3(1888), 256, 0, stream>>>(hb + PD0, w1b, s1);

  finalize_kernel<<<1, 256, 0, stream>>>(hs, ht, s0, s1, tc, y, out);
}

// Round 8
// 128.576 us; speedup vs baseline: 2.3769x; 1.2180x over previous
//
#include <hip/hip_runtime.h>
#include <stdint.h>

#define NROWS 4096
#define NHID 1024
#define CC0 1675
#define CC1 5025
#define HEADSZ 1677
#define PD0 256
#define PD1 64
#define TSZ0 3350
#define TSZ1 45232
#define HPN (HEADSZ + PD0 + PD1)   // 1997: head + proj0 + proj1 fused B
#define TPC1 6
#define L2E 1.4426950408889634f
#define LN2 0.6931471805599453f

typedef __attribute__((ext_vector_type(8))) __bf16 bf16x8;
typedef __attribute__((ext_vector_type(4))) float f32x4;

__device__ __forceinline__ unsigned short f2bf(float f) {
  union { float f; uint32_t u; } v; v.f = f;
  return (unsigned short)((v.u + 0x7FFFu + ((v.u >> 16) & 1u)) >> 16);
}
__device__ __forceinline__ float bfl(uint32_t u) {
  union { uint32_t u; float f; } v; v.u = u << 16; return v.f;
}
__device__ __forceinline__ float bfh(uint32_t u) {
  union { uint32_t u; float f; } v; v.u = u & 0xFFFF0000u; return v.f;
}
__device__ __forceinline__ float bf1(unsigned short u) {
  union { uint32_t u; float f; } v; v.u = ((uint32_t)u) << 16; return v.f;
}
#define EXP2(x) __builtin_amdgcn_exp2f(x)

// ---- single fused conversion kernel (sizes in float4 units, compile-time) --
#define CV1 1048576
#define CV2 1477888
#define CV3 1543424
#define CV4 1559808
#define CV5 1774208
#define CV6 2497920
__global__ void conv_all(const float* __restrict__ x, const float* __restrict__ hw,
                         const float* __restrict__ p0, const float* __restrict__ p1,
                         const float* __restrict__ w0, const float* __restrict__ w1,
                         unsigned short* __restrict__ dst) {
  int stride = gridDim.x * blockDim.x;
  for (int i = blockIdx.x * blockDim.x + threadIdx.x; i < CV6; i += stride) {
    const float* src; int off; float sc;
    if (i < CV1)      { src = x;  off = i;       sc = 1.f; }
    else if (i < CV2) { src = hw; off = i - CV1; sc = L2E; }
    else if (i < CV3) { src = p0; off = i - CV2; sc = 1.f; }
    else if (i < CV4) { src = p1; off = i - CV3; sc = 1.f; }
    else if (i < CV5) { src = w0; off = i - CV4; sc = L2E; }
    else              { src = w1; off = i - CV5; sc = L2E; }
    float4 v = reinterpret_cast<const float4*>(src)[off];
    ushort4 o;
    o.x = f2bf(v.x * sc); o.y = f2bf(v.y * sc);
    o.z = f2bf(v.z * sc); o.w = f2bf(v.w * sc);
    reinterpret_cast<ushort4*>(dst)[i] = o;
  }
}

#define GLOAD(g, l) __builtin_amdgcn_global_load_lds( \
    (const __attribute__((address_space(1))) uint32_t*)(const void*)(g), \
    (__attribute__((address_space(3))) uint32_t*)(void*)(l), 16, 0, 0)

// Involution swizzle on byte offsets within an 8KB [128][32]-bf16 tile:
// XOR bits 4-6 with bits 7-9. Bank-verified (round 2): conflicts 0.
#define SWZB(L) ((L) ^ ((((L) >> 7) & 7) << 4))

// ---------------- LDS ring-pipeline GEMM (head+proj, cluster 0) ------------
// 3-buffer ring, counted vmcnt(4): stage s+2 in flight while computing s.
__global__ __launch_bounds__(256, 2)
void gemm_fused(const unsigned short* __restrict__ A, int lda,
                const unsigned short* __restrict__ B, int ldb,
                int N, int K, int tpc,
                const float* __restrict__ bias,
                float* __restrict__ sum_out,
                unsigned short* __restrict__ Cout, int ldc,
                int coutStart) {
  __shared__ __align__(16) unsigned short As[3][128 * 32];
  __shared__ __align__(16) unsigned short Bs[3][128 * 32];
  const int tid = threadIdx.x;
  const int lane = tid & 63;
  const int wid = tid >> 6;
  const int wrow = (wid >> 1) * 64;
  const int wcol = (wid & 1) * 64;
  const int lr = lane & 15, lg = lane >> 4;

  const int cpx = gridDim.x >> 3;
  const int sid = ((int)blockIdx.x & 7) * cpx + ((int)blockIdx.x >> 3);
  const int rowBlk = sid & 31;
  const int colChunk = sid >> 5;
  const int brow = rowBlk * 128;
  const int nTiles = (N + 127) >> 7;
  const int tile0 = colChunk * tpc;
  const int tile1 = min(tile0 + tpc, nTiles);
  const int nsteps = (tile1 - tile0) * (K >> 5);
  const int rowBase = brow + wrow;

  float sacc[4][4];
#pragma unroll
  for (int m = 0; m < 4; ++m)
#pragma unroll
    for (int r = 0; r < 4; ++r) sacc[m][r] = 0.f;

  auto stage = [&](int b, int tt, int kk) {
#pragma unroll
    for (int c = 0; c < 2; ++c) {
      int g = wid * 128 + c * 64 + lane;
      int L = g * 16;
      int S = SWZB(L);
      int row = S >> 6, ko = (S >> 4) & 3;
      GLOAD(A + (size_t)(brow + row) * lda + kk + ko * 8, (char*)As[b] + L);
      int bsrc = tt * 128 + row; bsrc = bsrc < N ? bsrc : N - 1;
      GLOAD(B + (size_t)bsrc * ldb + kk + ko * 8, (char*)Bs[b] + L);
    }
  };

  f32x4 acc[4][4];
#pragma unroll
  for (int m = 0; m < 4; ++m)
#pragma unroll
    for (int n = 0; n < 4; ++n) acc[m][n] = (f32x4){0.f, 0.f, 0.f, 0.f};

  int tp = tile0, kp = 0;
  auto adv = [&](int& t, int& k) { k += 32; if (k == K) { k = 0; ++t; } };
  stage(0, tp, kp); adv(tp, kp);
  if (nsteps > 1) { stage(1, tp, kp); adv(tp, kp); }

  int tile = tile0, k0 = 0;
  for (int s = 0; s < nsteps; ++s) {
    if (s + 1 < nsteps) asm volatile("s_waitcnt vmcnt(4)" ::: "memory");
    else                asm volatile("s_waitcnt vmcnt(0)" ::: "memory");
    __builtin_amdgcn_s_barrier();
    if (s + 2 < nsteps) { stage((s + 2) % 3, tp, kp); adv(tp, kp); }

    const int cur = s % 3;
    int k0n = k0 + 32, tn = tile;
    if (k0n == K) { k0n = 0; tn = tile + 1; }

    bf16x8 af[4], bfv[4];
#pragma unroll
    for (int m = 0; m < 4; ++m)
      af[m] = *(const bf16x8*)((const char*)As[cur] +
                               SWZB((wrow + m * 16 + lr) * 64 + lg * 16));
#pragma unroll
    for (int n = 0; n < 4; ++n)
      bfv[n] = *(const bf16x8*)((const char*)Bs[cur] +
                                SWZB((wcol + n * 16 + lr) * 64 + lg * 16));
#pragma unroll
    for (int m = 0; m < 4; ++m)
#pragma unroll
      for (int n = 0; n < 4; ++n)
        acc[m][n] = __builtin_amdgcn_mfma_f32_16x16x32_bf16(af[m], bfv[n], acc[m][n], 0, 0, 0);

    if (tn != tile) {
      const int cb = tile * 128 + wcol;
#pragma unroll
      for (int m = 0; m < 4; ++m)
#pragma unroll
        for (int n = 0; n < 4; ++n) {
#pragma unroll
          for (int r = 0; r < 4; ++r) {
            int col = cb + n * 16 + lr;
            if (col < N) {
              float v = acc[m][n][r];
              if (Cout && col >= coutStart) {
                int row = rowBase + m * 16 + lg * 4 + r;
                Cout[(size_t)row * ldc + (col - coutStart)] = f2bf(v);
              } else {
                if (bias) v = fmaf(bias[col], L2E, v);  // v already log2e-scaled
                sacc[m][r] += EXP2(v);
              }
            }
          }
          acc[m][n] = (f32x4){0.f, 0.f, 0.f, 0.f};
        }
    }
    tile = tn; k0 = k0n;
  }

#pragma unroll
  for (int m = 0; m < 4; ++m)
#pragma unroll
    for (int r = 0; r < 4; ++r) {
      float s = sacc[m][r];
      s += __shfl_xor(s, 1); s += __shfl_xor(s, 2);
      s += __shfl_xor(s, 4); s += __shfl_xor(s, 8);
      if (lr == 0) atomicAdd(&sum_out[rowBase + m * 16 + lg * 4 + r], s);
    }
}

// ------------- cluster 1 v3: A-in-reg + B via global_load_lds ring ---------
// A = hb+PD0 [4096 x 64] (lda=320): af[4][2] persistent (32 VGPR, loaded once).
// B tile = 128 cols x 64 K = 16KB LDS, 3-buffer ring, counted vmcnt(4).
// B LDS tile [128 col][128 B] swizzled: byte ^= ((col&7)<<4), pre-swizzled
// source (linear DMA dest), same involution on ds_read. Bank check: 2-way.
// Compute in two 32-col halves -> only 32 acc regs live (occupancy!).
__global__ __launch_bounds__(256, 2)
void gemm_c1_lds(const unsigned short* __restrict__ A,
                 const unsigned short* __restrict__ B,
                 float* __restrict__ sum_out) {
  __shared__ __align__(16) unsigned short Bs[3][128 * 64];  // 3 x 16KB
  const int tid = threadIdx.x;
  const int lane = tid & 63;
  const int wid = tid >> 6;
  const int lr = lane & 15, lg = lane >> 4;

  const int cpx = gridDim.x >> 3;            // 1888/8 = 236, exact
  const int sid = ((int)blockIdx.x & 7) * cpx + ((int)blockIdx.x >> 3);
  const int rowBlk = sid & 31;
  const int colChunk = sid >> 5;
  const int rowBase = rowBlk * 128 + (wid >> 1) * 64;
  const int wcol = (wid & 1) * 64;
  const int tile0 = colChunk * TPC1;

  // staging source offsets (constant across tiles): chunk c covers LDS bytes
  // (c*256+tid)*16; source byte S = L ^ (((L>>7)&7)<<4) -> col=S>>7, kb=S&127
  int colOff[4], srcOff[4];
#pragma unroll
  for (int c = 0; c < 4; ++c) {
    int L = (c * 256 + tid) * 16;
    int S = L ^ (((L >> 7) & 7) << 4);
    colOff[c] = S >> 7;
    srcOff[c] = (S & 127) >> 1;
  }

  auto stage = [&](int b, int t) {
#pragma unroll
    for (int c = 0; c < 4; ++c) {
      int gc = t * 128 + colOff[c];
      gc = gc < TSZ1 ? gc : TSZ1 - 1;        // clamp OOB (last tile only)
      GLOAD(B + (size_t)gc * PD1 + srcOff[c],
            (char*)Bs[b] + (c * 256 + tid) * 16);
    }
  };

  // A fragments: loaded once (tile-invariant). 32 VGPRs.
  bf16x8 af[4][2];
#pragma unroll
  for (int m = 0; m < 4; ++m) {
    const unsigned short* p = A + (size_t)(rowBase + m * 16 + lr) * (PD0 + PD1) + lg * 8;
    af[m][0] = *(const bf16x8*)p;
    af[m][1] = *(const bf16x8*)(p + 32);
  }

  float sacc[4][4];
#pragma unroll
  for (int m = 0; m < 4; ++m)
#pragma unroll
    for (int r = 0; r < 4; ++r) sacc[m][r] = 0.f;

  stage(0, tile0);
  stage(1, tile0 + 1);

#pragma unroll 1
  for (int s = 0; s < TPC1; ++s) {
    if (s + 1 < TPC1) asm volatile("s_waitcnt vmcnt(4)" ::: "memory");
    else              asm volatile("s_waitcnt vmcnt(0)" ::: "memory");
    __builtin_amdgcn_s_barrier();            // stage(s) landed; compute(s-1) done
    if (s + 2 < TPC1) stage((s + 2) % 3, tile0 + s + 2);

    const int cur = s % 3;
    const int cb = (tile0 + s) * 128 + wcol;
    const int full = (cb + 63 < TSZ1);       // wave-uniform boundary flag

#pragma unroll
    for (int nh = 0; nh < 2; ++nh) {
      bf16x8 bf[2][2];
#pragma unroll
      for (int nn = 0; nn < 2; ++nn) {
        int ccol = wcol + (nh * 2 + nn) * 16 + lr;
#pragma unroll
        for (int kh = 0; kh < 2; ++kh) {
          int L = ccol * 128 + kh * 64 + lg * 16;
          bf[nn][kh] = *(const bf16x8*)((const char*)Bs[cur] +
                                        (L ^ ((ccol & 7) << 4)));
        }
      }
      f32x4 acc[4][2];
#pragma unroll
      for (int m = 0; m < 4; ++m)
#pragma unroll
        for (int nn = 0; nn < 2; ++nn) {
          f32x4 a = (f32x4){0.f, 0.f, 0.f, 0.f};
          a = __builtin_amdgcn_mfma_f32_16x16x32_bf16(af[m][0], bf[nn][0], a, 0, 0, 0);
          a = __builtin_amdgcn_mfma_f32_16x16x32_bf16(af[m][1], bf[nn][1], a, 0, 0, 0);
          acc[m][nn] = a;
        }
      if (full) {
#pragma unroll
        for (int m = 0; m < 4; ++m)
#pragma unroll
          for (int r = 0; r < 4; ++r)
            sacc[m][r] += EXP2(acc[m][0][r]) + EXP2(acc[m][1][r]);
      } else {
#pragma unroll
        for (int m = 0; m < 4; ++m)
#pragma unroll
          for (int r = 0; r < 4; ++r) {
            float t = 0.f;
#pragma unroll
            for (int nn = 0; nn < 2; ++nn)
              if (cb + (nh * 2 + nn) * 16 + lr < TSZ1) t += EXP2(acc[m][nn][r]);
            sacc[m][r] += t;
          }
      }
    }
  }

#pragma unroll
  for (int m = 0; m < 4; ++m)
#pragma unroll
    for (int r = 0; r < 4; ++r) {
      float s = sacc[m][r];
      s += __shfl_xor(s, 1); s += __shfl_xor(s, 2);
      s += __shfl_xor(s, 4); s += __shfl_xor(s, 8);
      if (lr == 0) atomicAdd(&sum_out[rowBase + m * 16 + lg * 4 + r], s);
    }
}

// One wave per row: target logits via direct dot products.
__global__ void target_logits(const unsigned short* __restrict__ xb,
                              const unsigned short* __restrict__ hwb,
                              const float* __restrict__ head_b,
                              const unsigned short* __restrict__ hb,
                              const unsigned short* __restrict__ w0b,
                              const unsigned short* __restrict__ w1b,
                              const int* __restrict__ y,
                              float* __restrict__ ht, float* __restrict__ tc) {
  int row = blockIdx.x * 4 + (threadIdx.x >> 6);
  int lane = threadIdx.x & 63;
  int yv = y[row];
  int th = yv < CC0 ? yv : (yv < CC1 ? CC0 : CC0 + 1);

  const unsigned short* xr = xb + (size_t)row * NHID + lane * 16;
  const unsigned short* wr = hwb + (size_t)th * NHID + lane * 16;
  uint4 xa = *(const uint4*)xr,       wa = *(const uint4*)wr;
  uint4 xc = *(const uint4*)(xr + 8), wc = *(const uint4*)(wr + 8);
  float s = 0.f;
  uint32_t xs[8] = {xa.x, xa.y, xa.z, xa.w, xc.x, xc.y, xc.z, xc.w};
  uint32_t ws[8] = {wa.x, wa.y, wa.z, wa.w, wc.x, wc.y, wc.z, wc.w};
#pragma unroll
  for (int j = 0; j < 8; ++j)
    s += bfl(xs[j]) * bfl(ws[j]) + bfh(xs[j]) * bfh(ws[j]);
#pragma unroll
  for (int d = 1; d < 64; d <<= 1) s += __shfl_xor(s, d);

  float cl = 0.f;
  if (yv >= CC0) {
    if (yv < CC1) {
      int rel = yv - CC0;
      const unsigned short* hr = hb + (size_t)row * (PD0 + PD1) + lane * 4;
      const unsigned short* w0r = w0b + (size_t)rel * PD0 + lane * 4;
      uint2 ha = *(const uint2*)hr, wa0 = *(const uint2*)w0r;
      cl = bfl(ha.x) * bfl(wa0.x) + bfh(ha.x) * bfh(wa0.x)
         + bfl(ha.y) * bfl(wa0.y) + bfh(ha.y) * bfh(wa0.y);
    } else {
      int rel = yv - CC1;
      cl = bf1(hb[(size_t)row * (PD0 + PD1) + PD0 + lane])
         * bf1(w1b[(size_t)rel * PD1 + lane]);
    }
#pragma unroll
    for (int d = 1; d < 64; d <<= 1) cl += __shfl_xor(cl, d);
  }
  if (lane == 0) { ht[row] = s * LN2 + head_b[th]; tc[row] = (yv < CC0) ? 0.f : cl; }
}

// Per-row loss + parallel mean reduction (grid 16 x 256). out[NROWS] must be
// zeroed before launch (4-byte memset). log via fast log2 * ln2.
__global__ void rowloss(const float* __restrict__ hs, const float* __restrict__ ht,
                        const float* __restrict__ s0, const float* __restrict__ s1,
                        const float* __restrict__ tc,
                        const int* __restrict__ y, float* __restrict__ out) {
  int n = blockIdx.x * 256 + threadIdx.x;
  int yv = y[n];
  float o = ht[n] - __builtin_amdgcn_logf(hs[n]) * LN2;
  if (yv >= CC0)
    o += tc[n] * LN2 - __builtin_amdgcn_logf(yv < CC1 ? s0[n] : s1[n]) * LN2;
  out[n] = o;
  float l = o;
#pragma unroll
  for (int d = 1; d < 64; d <<= 1) l += __shfl_xor(l, d);
  __shared__ float red[4];
  if ((threadIdx.x & 63) == 0) red[threadIdx.x >> 6] = l;
  __syncthreads();
  if (threadIdx.x == 0)
    atomicAdd(&out[NROWS], -(red[0] + red[1] + red[2] + red[3]) / (float)NROWS);
}

extern "C" void kernel_launch(void* const* d_in, const int* in_sizes, int n_in,
                              void* d_out, int out_size, void* d_ws, size_t ws_size,
                              hipStream_t stream) {
  const float* x      = (const float*)d_in[0];
  const int*   y      = (const int*)d_in[1];
  const float* head_w = (const float*)d_in[2];
  const float* head_b = (const float*)d_in[3];
  const float* proj0  = (const float*)d_in[4];
  const float* w0     = (const float*)d_in[5];
  const float* proj1  = (const float*)d_in[6];
  const float* w1     = (const float*)d_in[7];
  float* out = (float*)d_out;

  char* wp = (char*)d_ws;
  unsigned short* xb  = (unsigned short*)wp; wp += (size_t)NROWS * NHID * 2;
  unsigned short* hpb = (unsigned short*)wp; wp += (size_t)HPN * NHID * 2;
  unsigned short* w0b = (unsigned short*)wp; wp += (size_t)TSZ0 * PD0 * 2;
  unsigned short* w1b = (unsigned short*)wp; wp += (size_t)TSZ1 * PD1 * 2;
  unsigned short* hb  = (unsigned short*)wp; wp += (size_t)NROWS * (PD0 + PD1) * 2;
  float* hs = (float*)wp; wp += NROWS * 4;
  float* s0 = (float*)wp; wp += NROWS * 4;
  float* s1 = (float*)wp; wp += NROWS * 4;
  float* ht = (float*)wp; wp += NROWS * 4;
  float* tc = (float*)wp; wp += NROWS * 4;

  hipMemsetAsync(hs, 0, 3 * NROWS * 4, stream);      // zero hs, s0, s1
  hipMemsetAsync(out + NROWS, 0, 4, stream);         // zero loss accumulator

  // single fused conversion (head_w/w0/w1 pre-scaled by log2e)
  conv_all<<<dim3(2048), 256, 0, stream>>>(x, head_w, proj0, proj1, w0, w1, xb);

  // head + proj fused: cols [0,1677) -> exp2-sum; cols [1677,1997) -> hb store
  gemm_fused<<<dim3(512), 256, 0, stream>>>(
      xb, NHID, hpb, NHID, HPN, NHID, 1,
      head_b, hs, hb, PD0 + PD1, HEADSZ);
  // target logits (needs hb) — one wave per row
  target_logits<<<dim3(NROWS / 4), 256, 0, stream>>>(
      xb, hpb, head_b, hb, w0b, w1b, y, ht, tc);
  // cluster 0: nTiles=27, tpc=1 -> 27 chunks x 32 = 864 blocks, 8-step chains
  gemm_fused<<<dim3(864), 256, 0, stream>>>(
      hb, PD0 + PD1, w0b, PD0, TSZ0, PD0, 1,
      nullptr, s0, nullptr, 0, 0);
  // cluster 1 v3: A-in-reg + B DMA ring: 59 chunks x 32 rowBlks = 1888 blocks
  gemm_c1_lds<<<dim3(1888), 256, 0, stream>>>(hb + PD0, w1b, s1);

  // per-row loss + mean (out[NROWS] pre-zeroed)
  rowloss<<<dim3(NROWS / 256), 256, 0, stream>>>(hs, ht, s0, s1, tc, y, out);
}

// Round 10
// 107.206 us; speedup vs baseline: 2.8507x; 1.1993x over previous
//
#include <hip/hip_runtime.h>
#include <stdint.h>

#define NROWS 4096
#define NHID 1024
#define CC0 1675
#define CC1 5025
#define HEADSZ 1677
#define PD0 256
#define PD1 64
#define TSZ0 3350
#define TSZ1 45232
#define HPN (HEADSZ + PD0 + PD1)   // 1997: head + proj0 + proj1 fused B
#define TPC1 6
#define L2E 1.4426950408889634f
#define LN2 0.6931471805599453f

// fused_tail grid segmentation (each segment start divisible by 8 so the
// per-segment XCD swizzle stays XCD-aligned)
#define NB_C0 864        // 27 colChunks x 32 rowBlks
#define NB_C1 1888       // 59 colChunks x 32 rowBlks
#define NB_TG 1024       // 4096 rows / 4 per block
#define NB_TAIL (NB_C0 + NB_C1 + NB_TG)

typedef __attribute__((ext_vector_type(8))) __bf16 bf16x8;
typedef __attribute__((ext_vector_type(4))) float f32x4;

__device__ __forceinline__ unsigned short f2bf(float f) {
  union { float f; uint32_t u; } v; v.f = f;
  return (unsigned short)((v.u + 0x7FFFu + ((v.u >> 16) & 1u)) >> 16);
}
__device__ __forceinline__ float bfl(uint32_t u) {
  union { uint32_t u; float f; } v; v.u = u << 16; return v.f;
}
__device__ __forceinline__ float bfh(uint32_t u) {
  union { uint32_t u; float f; } v; v.u = u & 0xFFFF0000u; return v.f;
}
__device__ __forceinline__ float bf1(unsigned short u) {
  union { uint32_t u; float f; } v; v.u = ((uint32_t)u) << 16; return v.f;
}
#define EXP2(x) __builtin_amdgcn_exp2f(x)

// ---- single fused conversion kernel (sizes in float4 units, compile-time) --
#define CV1 1048576
#define CV2 1477888
#define CV3 1543424
#define CV4 1559808
#define CV5 1774208
#define CV6 2497920
__global__ void conv_all(const float* __restrict__ x, const float* __restrict__ hw,
                         const float* __restrict__ p0, const float* __restrict__ p1,
                         const float* __restrict__ w0, const float* __restrict__ w1,
                         unsigned short* __restrict__ dst) {
  int stride = gridDim.x * blockDim.x;
  for (int i = blockIdx.x * blockDim.x + threadIdx.x; i < CV6; i += stride) {
    const float* src; int off; float sc;
    if (i < CV1)      { src = x;  off = i;       sc = 1.f; }
    else if (i < CV2) { src = hw; off = i - CV1; sc = L2E; }
    else if (i < CV3) { src = p0; off = i - CV2; sc = 1.f; }
    else if (i < CV4) { src = p1; off = i - CV3; sc = 1.f; }
    else if (i < CV5) { src = w0; off = i - CV4; sc = L2E; }
    else              { src = w1; off = i - CV5; sc = L2E; }
    float4 v = reinterpret_cast<const float4*>(src)[off];
    ushort4 o;
    o.x = f2bf(v.x * sc); o.y = f2bf(v.y * sc);
    o.z = f2bf(v.z * sc); o.w = f2bf(v.w * sc);
    reinterpret_cast<ushort4*>(dst)[i] = o;
  }
}

#define GLOAD(g, l) __builtin_amdgcn_global_load_lds( \
    (const __attribute__((address_space(1))) uint32_t*)(const void*)(g), \
    (__attribute__((address_space(3))) uint32_t*)(void*)(l), 16, 0, 0)

// Involution swizzle on byte offsets within an 8KB [128][32]-bf16 tile:
// XOR bits 4-6 with bits 7-9. Bank-verified (round 2): conflicts 0.
#define SWZB(L) ((L) ^ ((((L) >> 7) & 7) << 4))

// --------------- shared GEMM core (128-tile, 3-buffer counted ring) --------
// AsB/BsB: LDS bases, 3 x 4096 ushort each. Epilogue: Cout cols >= coutStart
// stored bf16; else exp2-sum into sacc -> one atomic per row.
__device__ __forceinline__
void gemm_core(const unsigned short* __restrict__ A, int lda,
               const unsigned short* __restrict__ B, int ldb,
               int N, int K, int tile0, int tile1, int brow,
               const float* __restrict__ bias,
               float* __restrict__ sum_out,
               unsigned short* __restrict__ Cout, int ldc, int coutStart,
               unsigned short* AsB, unsigned short* BsB) {
  const int tid = threadIdx.x;
  const int lane = tid & 63;
  const int wid = tid >> 6;
  const int wrow = (wid >> 1) * 64;
  const int wcol = (wid & 1) * 64;
  const int lr = lane & 15, lg = lane >> 4;
  const int nsteps = (tile1 - tile0) * (K >> 5);
  const int rowBase = brow + wrow;

  float sacc[4][4];
#pragma unroll
  for (int m = 0; m < 4; ++m)
#pragma unroll
    for (int r = 0; r < 4; ++r) sacc[m][r] = 0.f;

  auto stage = [&](int b, int tt, int kk) {
#pragma unroll
    for (int c = 0; c < 2; ++c) {
      int g = wid * 128 + c * 64 + lane;
      int L = g * 16;
      int S = SWZB(L);
      int row = S >> 6, ko = (S >> 4) & 3;
      GLOAD(A + (size_t)(brow + row) * lda + kk + ko * 8, (char*)AsB + b * 8192 + L);
      int bsrc = tt * 128 + row; bsrc = bsrc < N ? bsrc : N - 1;
      GLOAD(B + (size_t)bsrc * ldb + kk + ko * 8, (char*)BsB + b * 8192 + L);
    }
  };

  f32x4 acc[4][4];
#pragma unroll
  for (int m = 0; m < 4; ++m)
#pragma unroll
    for (int n = 0; n < 4; ++n) acc[m][n] = (f32x4){0.f, 0.f, 0.f, 0.f};

  int tp = tile0, kp = 0;
  auto adv = [&](int& t, int& k) { k += 32; if (k == K) { k = 0; ++t; } };
  stage(0, tp, kp); adv(tp, kp);
  if (nsteps > 1) { stage(1, tp, kp); adv(tp, kp); }

  int tile = tile0, k0 = 0;
  for (int s = 0; s < nsteps; ++s) {
    if (s + 1 < nsteps) asm volatile("s_waitcnt vmcnt(4)" ::: "memory");
    else                asm volatile("s_waitcnt vmcnt(0)" ::: "memory");
    __builtin_amdgcn_s_barrier();
    if (s + 2 < nsteps) { stage((s + 2) % 3, tp, kp); adv(tp, kp); }

    const int cur = s % 3;
    int k0n = k0 + 32, tn = tile;
    if (k0n == K) { k0n = 0; tn = tile + 1; }

    bf16x8 af[4], bfv[4];
#pragma unroll
    for (int m = 0; m < 4; ++m)
      af[m] = *(const bf16x8*)((const char*)AsB + cur * 8192 +
                               SWZB((wrow + m * 16 + lr) * 64 + lg * 16));
#pragma unroll
    for (int n = 0; n < 4; ++n)
      bfv[n] = *(const bf16x8*)((const char*)BsB + cur * 8192 +
                                SWZB((wcol + n * 16 + lr) * 64 + lg * 16));
#pragma unroll
    for (int m = 0; m < 4; ++m)
#pragma unroll
      for (int n = 0; n < 4; ++n)
        acc[m][n] = __builtin_amdgcn_mfma_f32_16x16x32_bf16(af[m], bfv[n], acc[m][n], 0, 0, 0);

    if (tn != tile) {
      const int cb = tile * 128 + wcol;
#pragma unroll
      for (int m = 0; m < 4; ++m)
#pragma unroll
        for (int n = 0; n < 4; ++n) {
#pragma unroll
          for (int r = 0; r < 4; ++r) {
            int col = cb + n * 16 + lr;
            if (col < N) {
              float v = acc[m][n][r];
              if (Cout && col >= coutStart) {
                int row = rowBase + m * 16 + lg * 4 + r;
                Cout[(size_t)row * ldc + (col - coutStart)] = f2bf(v);
              } else {
                if (bias) v = fmaf(bias[col], L2E, v);  // v already log2e-scaled
                sacc[m][r] += EXP2(v);
              }
            }
          }
          acc[m][n] = (f32x4){0.f, 0.f, 0.f, 0.f};
        }
    }
    tile = tn; k0 = k0n;
  }

#pragma unroll
  for (int m = 0; m < 4; ++m)
#pragma unroll
    for (int r = 0; r < 4; ++r) {
      float s = sacc[m][r];
      s += __shfl_xor(s, 1); s += __shfl_xor(s, 2);
      s += __shfl_xor(s, 4); s += __shfl_xor(s, 8);
      if (lr == 0) atomicAdd(&sum_out[rowBase + m * 16 + lg * 4 + r], s);
    }
}

// --------------- head+proj GEMM kernel (512 blocks -> 2/CU exactly) --------
__global__ __launch_bounds__(256, 2)
void gemm_head(const unsigned short* __restrict__ A,
               const unsigned short* __restrict__ B,
               const float* __restrict__ bias,
               float* __restrict__ sum_out,
               unsigned short* __restrict__ Cout) {
  __shared__ __align__(16) unsigned short As[3 * 4096];
  __shared__ __align__(16) unsigned short Bs[3 * 4096];
  const int cpx = 512 >> 3;
  const int sid = ((int)blockIdx.x & 7) * cpx + ((int)blockIdx.x >> 3);
  const int rowBlk = sid & 31;
  const int colChunk = sid >> 5;       // 16 chunks, tpc=1
  gemm_core(A, NHID, B, NHID, HPN, NHID, colChunk, colChunk + 1, rowBlk * 128,
            bias, sum_out, Cout, PD0 + PD1, HEADSZ, As, Bs);
}

// ------- fused tail: c0 GEMM | c1 DMA-ring GEMM | target-logit gather ------
// Register-criticality note: (256,3) => ~170 unified regs/wave. c0 branch
// needs ~148, c1 ~100, target ~60. (256,4) spills (round 6: 3x regression).
__global__ __launch_bounds__(256, 3)
void fused_tail(const unsigned short* __restrict__ hb,
                const unsigned short* __restrict__ w0b,
                const unsigned short* __restrict__ w1b,
                const unsigned short* __restrict__ xb,
                const unsigned short* __restrict__ hwb,
                const float* __restrict__ head_b,
                const int* __restrict__ y,
                float* __restrict__ s0, float* __restrict__ s1,
                float* __restrict__ ht, float* __restrict__ tc) {
  __shared__ __align__(16) unsigned short lds[6 * 4096];   // 48KB union
  const int bid = blockIdx.x;

  if (bid < NB_C0) {
    // ---- cluster 0: hb[:, :256] @ w0^T, K=256, tpc=1 (8-step ring) ----
    const int cpx = NB_C0 >> 3;        // 108
    const int sid = (bid & 7) * cpx + (bid >> 3);
    const int rowBlk = sid & 31;
    const int colChunk = sid >> 5;     // [0,27)
    gemm_core(hb, PD0 + PD1, w0b, PD0, TSZ0, PD0, colChunk, colChunk + 1,
              rowBlk * 128, nullptr, s0, nullptr, 0, 0, lds, lds + 3 * 4096);
    return;
  }

  if (bid < NB_C0 + NB_C1) {
    // ---- cluster 1: A-in-reg + B DMA ring (K=64), 6 tiles/chunk ----
    const int b1 = bid - NB_C0;
    const int tid = threadIdx.x;
    const int lane = tid & 63;
    const int wid = tid >> 6;
    const int lr = lane & 15, lg = lane >> 4;
    const int cpx = NB_C1 >> 3;        // 236
    const int sid = (b1 & 7) * cpx + (b1 >> 3);
    const int rowBlk = sid & 31;
    const int colChunk = sid >> 5;     // [0,59)
    const int rowBase = rowBlk * 128 + (wid >> 1) * 64;
    const int wcol = (wid & 1) * 64;
    const int tile0 = colChunk * TPC1;

    int colOff[4], srcOff[4];
#pragma unroll
    for (int c = 0; c < 4; ++c) {
      int L = (c * 256 + tid) * 16;
      int S = L ^ (((L >> 7) & 7) << 4);
      colOff[c] = S >> 7;
      srcOff[c] = (S & 127) >> 1;
    }
    auto stage = [&](int b, int t) {
#pragma unroll
      for (int c = 0; c < 4; ++c) {
        int gc = t * 128 + colOff[c];
        gc = gc < TSZ1 ? gc : TSZ1 - 1;
        GLOAD(w1b + (size_t)gc * PD1 + srcOff[c],
              (char*)lds + b * 16384 + (c * 256 + tid) * 16);
      }
    };

    bf16x8 af[4][2];
#pragma unroll
    for (int m = 0; m < 4; ++m) {
      const unsigned short* p = hb + PD0 +
          (size_t)(rowBase + m * 16 + lr) * (PD0 + PD1) + lg * 8;
      af[m][0] = *(const bf16x8*)p;
      af[m][1] = *(const bf16x8*)(p + 32);
    }

    float sacc[4][4];
#pragma unroll
    for (int m = 0; m < 4; ++m)
#pragma unroll
      for (int r = 0; r < 4; ++r) sacc[m][r] = 0.f;

    stage(0, tile0);
    stage(1, tile0 + 1);

#pragma unroll 1
    for (int s = 0; s < TPC1; ++s) {
      if (s + 1 < TPC1) asm volatile("s_waitcnt vmcnt(4)" ::: "memory");
      else              asm volatile("s_waitcnt vmcnt(0)" ::: "memory");
      __builtin_amdgcn_s_barrier();
      if (s + 2 < TPC1) stage((s + 2) % 3, tile0 + s + 2);

      const int cur = s % 3;
      const int cb = (tile0 + s) * 128 + wcol;
      const int full = (cb + 63 < TSZ1);

#pragma unroll
      for (int nh = 0; nh < 2; ++nh) {
        bf16x8 bf[2][2];
#pragma unroll
        for (int nn = 0; nn < 2; ++nn) {
          int ccol = wcol + (nh * 2 + nn) * 16 + lr;
#pragma unroll
          for (int kh = 0; kh < 2; ++kh) {
            int L = ccol * 128 + kh * 64 + lg * 16;
            bf[nn][kh] = *(const bf16x8*)((const char*)lds + cur * 16384 +
                                          (L ^ ((ccol & 7) << 4)));
          }
        }
        f32x4 acc[4][2];
#pragma unroll
        for (int m = 0; m < 4; ++m)
#pragma unroll
          for (int nn = 0; nn < 2; ++nn) {
            f32x4 a = (f32x4){0.f, 0.f, 0.f, 0.f};
            a = __builtin_amdgcn_mfma_f32_16x16x32_bf16(af[m][0], bf[nn][0], a, 0, 0, 0);
            a = __builtin_amdgcn_mfma_f32_16x16x32_bf16(af[m][1], bf[nn][1], a, 0, 0, 0);
            acc[m][nn] = a;
          }
        if (full) {
#pragma unroll
          for (int m = 0; m < 4; ++m)
#pragma unroll
            for (int r = 0; r < 4; ++r)
              sacc[m][r] += EXP2(acc[m][0][r]) + EXP2(acc[m][1][r]);
        } else {
#pragma unroll
          for (int m = 0; m < 4; ++m)
#pragma unroll
            for (int r = 0; r < 4; ++r) {
              float t = 0.f;
#pragma unroll
              for (int nn = 0; nn < 2; ++nn)
                if (cb + (nh * 2 + nn) * 16 + lr < TSZ1) t += EXP2(acc[m][nn][r]);
              sacc[m][r] += t;
            }
        }
      }
    }

#pragma unroll
    for (int m = 0; m < 4; ++m)
#pragma unroll
      for (int r = 0; r < 4; ++r) {
        float s = sacc[m][r];
        s += __shfl_xor(s, 1); s += __shfl_xor(s, 2);
        s += __shfl_xor(s, 4); s += __shfl_xor(s, 8);
        if (lr == 0) atomicAdd(&s1[rowBase + m * 16 + lg * 4 + r], s);
      }
    return;
  }

  // ---- target logits: one wave per row ----
  {
    const int b2 = bid - NB_C0 - NB_C1;
    int row = b2 * 4 + (threadIdx.x >> 6);
    int lane = threadIdx.x & 63;
    int yv = y[row];
    int th = yv < CC0 ? yv : (yv < CC1 ? CC0 : CC0 + 1);

    const unsigned short* xr = xb + (size_t)row * NHID + lane * 16;
    const unsigned short* wr = hwb + (size_t)th * NHID + lane * 16;
    uint4 xa = *(const uint4*)xr,       wa = *(const uint4*)wr;
    uint4 xc = *(const uint4*)(xr + 8), wc = *(const uint4*)(wr + 8);
    float s = 0.f;
    uint32_t xs[8] = {xa.x, xa.y, xa.z, xa.w, xc.x, xc.y, xc.z, xc.w};
    uint32_t ws[8] = {wa.x, wa.y, wa.z, wa.w, wc.x, wc.y, wc.z, wc.w};
#pragma unroll
    for (int j = 0; j < 8; ++j)
      s += bfl(xs[j]) * bfl(ws[j]) + bfh(xs[j]) * bfh(ws[j]);
#pragma unroll
    for (int d = 1; d < 64; d <<= 1) s += __shfl_xor(s, d);

    float cl = 0.f;
    if (yv >= CC0) {
      if (yv < CC1) {
        int rel = yv - CC0;
        const unsigned short* hr = hb + (size_t)row * (PD0 + PD1) + lane * 4;
        const unsigned short* w0r = w0b + (size_t)rel * PD0 + lane * 4;
        uint2 ha = *(const uint2*)hr, wa0 = *(const uint2*)w0r;
        cl = bfl(ha.x) * bfl(wa0.x) + bfh(ha.x) * bfh(wa0.x)
           + bfl(ha.y) * bfl(wa0.y) + bfh(ha.y) * bfh(wa0.y);
      } else {
        int rel = yv - CC1;
        cl = bf1(hb[(size_t)row * (PD0 + PD1) + PD0 + lane])
           * bf1(w1b[(size_t)rel * PD1 + lane]);
      }
#pragma unroll
      for (int d = 1; d < 64; d <<= 1) cl += __shfl_xor(cl, d);
    }
    if (lane == 0) { ht[row] = s * LN2 + head_b[th]; tc[row] = (yv < CC0) ? 0.f : cl; }
  }
}

// Per-row loss + parallel mean reduction (grid 16 x 256). out[NROWS] must be
// zeroed before launch. v_log_f32 is log2 -> * LN2.
__global__ void rowloss(const float* __restrict__ hs, const float* __restrict__ ht,
                        const float* __restrict__ s0, const float* __restrict__ s1,
                        const float* __restrict__ tc,
                        const int* __restrict__ y, float* __restrict__ out) {
  int n = blockIdx.x * 256 + threadIdx.x;
  int yv = y[n];
  float o = ht[n] - __builtin_amdgcn_logf(hs[n]) * LN2;
  if (yv >= CC0)
    o += tc[n] * LN2 - __builtin_amdgcn_logf(yv < CC1 ? s0[n] : s1[n]) * LN2;
  out[n] = o;
  float l = o;
#pragma unroll
  for (int d = 1; d < 64; d <<= 1) l += __shfl_xor(l, d);
  __shared__ float red[4];
  if ((threadIdx.x & 63) == 0) red[threadIdx.x >> 6] = l;
  __syncthreads();
  if (threadIdx.x == 0)
    atomicAdd(&out[NROWS], -(red[0] + red[1] + red[2] + red[3]) / (float)NROWS);
}

extern "C" void kernel_launch(void* const* d_in, const int* in_sizes, int n_in,
                              void* d_out, int out_size, void* d_ws, size_t ws_size,
                              hipStream_t stream) {
  const float* x      = (const float*)d_in[0];
  const int*   y      = (const int*)d_in[1];
  const float* head_w = (const float*)d_in[2];
  const float* head_b = (const float*)d_in[3];
  const float* proj0  = (const float*)d_in[4];
  const float* w0     = (const float*)d_in[5];
  const float* proj1  = (const float*)d_in[6];
  const float* w1     = (const float*)d_in[7];
  float* out = (float*)d_out;

  char* wp = (char*)d_ws;
  unsigned short* xb  = (unsigned short*)wp; wp += (size_t)NROWS * NHID * 2;
  unsigned short* hpb = (unsigned short*)wp; wp += (size_t)HPN * NHID * 2;
  unsigned short* w0b = (unsigned short*)wp; wp += (size_t)TSZ0 * PD0 * 2;
  unsigned short* w1b = (unsigned short*)wp; wp += (size_t)TSZ1 * PD1 * 2;
  unsigned short* hb  = (unsigned short*)wp; wp += (size_t)NROWS * (PD0 + PD1) * 2;
  float* hs = (float*)wp; wp += NROWS * 4;
  float* s0 = (float*)wp; wp += NROWS * 4;
  float* s1 = (float*)wp; wp += NROWS * 4;
  float* ht = (float*)wp; wp += NROWS * 4;
  float* tc = (float*)wp; wp += NROWS * 4;

  hipMemsetAsync(hs, 0, 3 * NROWS * 4, stream);      // zero hs, s0, s1
  hipMemsetAsync(out + NROWS, 0, 4, stream);         // zero loss accumulator

  // single fused conversion (head_w/w0/w1 pre-scaled by log2e)
  conv_all<<<dim3(2048), 256, 0, stream>>>(x, head_w, proj0, proj1, w0, w1, xb);

  // head + proj fused: cols [0,1677) -> exp2-sum; cols [1677,1997) -> hb store
  gemm_head<<<dim3(512), 256, 0, stream>>>(xb, hpb, head_b, hs, hb);

  // fused tail: c0 GEMM + c1 GEMM + target-logit gather, one dispatch
  fused_tail<<<dim3(NB_TAIL), 256, 0, stream>>>(
      hb, w0b, w1b, xb, hpb, head_b, y, s0, s1, ht, tc);

  // per-row loss + mean (out[NROWS] pre-zeroed)
  rowloss<<<dim3(NROWS / 256), 256, 0, stream>>>(hs, ht, s0, s1, tc, y, out);
}